// Round 1
// baseline (524.385 us; speedup 1.0000x reference)
//
#include <hip/hip_runtime.h>

#define S_LEN 2048
#define EMB   1024
#define NH    16
#define HD    64
#define BATCH_ 4
#define BHN   (BATCH_*NH)        // 64
#define M_ROWS (BATCH_*S_LEN)    // 8192
#define KDIM  1024
#define N_QKV 3072

typedef unsigned short u16;
typedef __attribute__((ext_vector_type(8))) short bf16x8;
typedef __attribute__((ext_vector_type(4))) float f32x4;

__device__ __forceinline__ u16 f2bf(float f) {
  unsigned u = __float_as_uint(f);
  u += 0x7fff + ((u >> 16) & 1);
  return (u16)(u >> 16);
}

__device__ __forceinline__ void load_lds16(const void* g, void* l) {
  __builtin_amdgcn_global_load_lds(
      (const __attribute__((address_space(1))) unsigned int*)g,
      (__attribute__((address_space(3))) unsigned int*)l, 16, 0, 0);
}

// ---------------- convert x -> bf16 ----------------
__global__ void cvt_x(const float4* __restrict__ in, ushort4* __restrict__ outb, int n4) {
  int i = blockIdx.x * blockDim.x + threadIdx.x;
  int stride = gridDim.x * blockDim.x;
  for (; i < n4; i += stride) {
    float4 v = in[i];
    ushort4 o;
    o.x = f2bf(v.x); o.y = f2bf(v.y); o.z = f2bf(v.z); o.w = f2bf(v.w);
    outb[i] = o;
  }
}

// ------------- transpose-convert W[R][C] f32 -> Wt[C][R] bf16 -------------
__global__ __launch_bounds__(256) void transpose_cvt(
    const float* __restrict__ W, u16* __restrict__ Wt, int R, int C) {
  __shared__ u16 t[64][65];
  int r0 = blockIdx.y * 64, c0 = blockIdx.x * 64;
  #pragma unroll
  for (int p = 0; p < 16; ++p) {
    int idx = p * 256 + threadIdx.x;
    int r = idx >> 6, c = idx & 63;
    t[r][c] = f2bf(W[(size_t)(r0 + r) * C + c0 + c]);
  }
  __syncthreads();
  #pragma unroll
  for (int p = 0; p < 16; ++p) {
    int idx = p * 256 + threadIdx.x;
    int cc = idx >> 6, rr = idx & 63;
    Wt[(size_t)(c0 + cc) * R + r0 + rr] = t[rr][cc];
  }
}

// ---------------- GEMM1: X[8192,1024] @ WaT^T -> Q,K,V^T (bf16) ----------------
__global__ __launch_bounds__(256) void gemm_qkv(
    const u16* __restrict__ A, const u16* __restrict__ Bt,
    const float* __restrict__ bias,
    u16* __restrict__ Qo, u16* __restrict__ Ko, u16* __restrict__ Vto) {
  __shared__ u16 As[128 * 32];
  __shared__ u16 Bs[128 * 32];
  const int tid = threadIdx.x;
  const int m0 = blockIdx.x * 128, n0 = blockIdx.y * 128;
  const int w = tid >> 6, lane = tid & 63, g = lane >> 4, ln = lane & 15;
  const int wm = (w >> 1) * 64, wn = (w & 1) * 64;

  f32x4 zero4 = {0.f, 0.f, 0.f, 0.f};
  f32x4 acc[4][4];
  #pragma unroll
  for (int mi = 0; mi < 4; ++mi)
    #pragma unroll
    for (int ni = 0; ni < 4; ++ni) acc[mi][ni] = zero4;

  for (int kt = 0; kt < KDIM / 32; ++kt) {
    #pragma unroll
    for (int p = 0; p < 2; ++p) {
      int idx = p * 256 + tid;
      int row = idx >> 2, sl = idx & 3;
      int ssl = sl ^ (row & 3);                   // pre-swizzled source slot
      load_lds16(A  + (size_t)(m0 + row) * KDIM + kt * 32 + ssl * 8, As + idx * 8);
      load_lds16(Bt + (size_t)(n0 + row) * KDIM + kt * 32 + ssl * 8, Bs + idx * 8);
    }
    __syncthreads();
    bf16x8 av[4], bv[4];
    #pragma unroll
    for (int mi = 0; mi < 4; ++mi) {
      int r = wm + mi * 16 + ln;
      av[mi] = *(const bf16x8*)&As[r * 32 + ((g ^ (r & 3)) * 8)];
    }
    #pragma unroll
    for (int ni = 0; ni < 4; ++ni) {
      int r = wn + ni * 16 + ln;
      bv[ni] = *(const bf16x8*)&Bs[r * 32 + ((g ^ (r & 3)) * 8)];
    }
    #pragma unroll
    for (int mi = 0; mi < 4; ++mi)
      #pragma unroll
      for (int ni = 0; ni < 4; ++ni)
        acc[mi][ni] = __builtin_amdgcn_mfma_f32_16x16x32_bf16(av[mi], bv[ni], acc[mi][ni], 0, 0, 0);
    __syncthreads();
  }

  // epilogue: bias add, bf16, scatter to Q [BH,S,D], K [BH,S,D], V^T [BH,D,S]
  #pragma unroll
  for (int ni = 0; ni < 4; ++ni) {
    int n = n0 + wn + ni * 16 + ln;
    float bb = bias[n];
    int which = n >> 10;             // 0=Q 1=K 2=V
    int e = n & 1023;
    int h = e >> 6, d = e & 63;
    #pragma unroll
    for (int mi = 0; mi < 4; ++mi) {
      int m = m0 + wm + mi * 16 + 4 * g;
      int b = m >> 11, s = m & 2047;
      size_t bh = (size_t)b * NH + h;
      #pragma unroll
      for (int jr = 0; jr < 4; ++jr) {
        u16 val = f2bf(acc[mi][ni][jr] + bb);
        if (which == 0)      Qo [(bh * S_LEN + s + jr) * HD + d] = val;
        else if (which == 1) Ko [(bh * S_LEN + s + jr) * HD + d] = val;
        else                 Vto[(bh * HD + d) * S_LEN + s + jr] = val;
      }
    }
  }
}

// ---------------- flash attention: Q,K [BH,S,D], V^T [BH,D,S] -> Y bf16 [B,S,E] ----------------
__global__ __launch_bounds__(256) void attn_kernel(
    const u16* __restrict__ Q, const u16* __restrict__ Kg,
    const u16* __restrict__ Vt, const int* __restrict__ amask,
    u16* __restrict__ Y) {
  __shared__ u16 Ks[64 * 64];
  __shared__ u16 Vs[64 * 64];          // [d][key] (swizzled)
  __shared__ u16 Ps[4][16 * 64];       // per-wave P tile (swizzled)
  __shared__ int mk[64];
  const int bh = blockIdx.y;
  const int b = bh >> 4, h = bh & 15;
  const int qblk = gridDim.x - 1 - blockIdx.x;   // launch long blocks first
  const int q0 = qblk * 64;
  const int tid = threadIdx.x, w = tid >> 6, lane = tid & 63, g = lane >> 4, ln = lane & 15;
  const int qr = q0 + w * 16;

  // Q fragments (resident whole kernel)
  bf16x8 aq[2];
  const u16* qp = Q + ((size_t)bh * S_LEN + qr + ln) * HD;
  aq[0] = *(const bf16x8*)(qp + g * 8);
  aq[1] = *(const bf16x8*)(qp + 32 + g * 8);

  f32x4 zero4 = {0.f, 0.f, 0.f, 0.f};
  f32x4 o[4];
  #pragma unroll
  for (int dblk = 0; dblk < 4; ++dblk) o[dblk] = zero4;
  float mrow[4], lrow[4];
  #pragma unroll
  for (int jr = 0; jr < 4; ++jr) { mrow[jr] = -__builtin_inff(); lrow[jr] = 0.f; }

  const int nt = qblk + 1;
  for (int kt = 0; kt < nt; ++kt) {
    // stage K tile [key][d] and V^T tile [d][key], swizzled source
    #pragma unroll
    for (int p = 0; p < 2; ++p) {
      int idx = p * 256 + tid;
      int row = idx >> 3, sl = idx & 7;
      int ssl = sl ^ (row & 7);
      load_lds16(Kg + ((size_t)bh * S_LEN + kt * 64 + row) * HD + ssl * 8, Ks + idx * 8);
      load_lds16(Vt + ((size_t)bh * HD + row) * S_LEN + kt * 64 + ssl * 8, Vs + idx * 8);
    }
    if (tid < 64) mk[tid] = amask[b * S_LEN + kt * 64 + tid];
    __syncthreads();

    // QK^T: S[16 q x 64 keys]
    f32x4 sa[4];
    #pragma unroll
    for (int kb = 0; kb < 4; ++kb) sa[kb] = zero4;
    #pragma unroll
    for (int kb = 0; kb < 4; ++kb) {
      int r = kb * 16 + ln;
      #pragma unroll
      for (int t = 0; t < 2; ++t) {
        bf16x8 bk = *(const bf16x8*)&Ks[r * 64 + (((4 * t + g) ^ (r & 7)) * 8)];
        sa[kb] = __builtin_amdgcn_mfma_f32_16x16x32_bf16(aq[t], bk, sa[kb], 0, 0, 0);
      }
    }

    // online softmax (rows 4g+jr, reduce across 16 lanes of the group)
    float pv[4][4];
    #pragma unroll
    for (int jr = 0; jr < 4; ++jr) {
      int qrow = qr + 4 * g + jr;
      float sc[4];
      float pm = -__builtin_inff();
      #pragma unroll
      for (int kb = 0; kb < 4; ++kb) {
        int key = kt * 64 + kb * 16 + ln;
        float s = sa[kb][jr] * 0.125f;
        if (key > qrow || mk[kb * 16 + ln] == 0) s = -__builtin_inff();
        sc[kb] = s;
        pm = fmaxf(pm, s);
      }
      pm = fmaxf(pm, __shfl_xor(pm, 1));
      pm = fmaxf(pm, __shfl_xor(pm, 2));
      pm = fmaxf(pm, __shfl_xor(pm, 4));
      pm = fmaxf(pm, __shfl_xor(pm, 8));
      float mN = fmaxf(mrow[jr], pm);
      float corr, psum = 0.f;
      if (mN <= -1e30f) {
        corr = 1.0f;
        #pragma unroll
        for (int kb = 0; kb < 4; ++kb) pv[jr][kb] = 0.f;
      } else {
        corr = __expf(mrow[jr] - mN);
        #pragma unroll
        for (int kb = 0; kb < 4; ++kb) {
          float p = __expf(sc[kb] - mN);
          pv[jr][kb] = p;
          psum += p;
        }
      }
      psum += __shfl_xor(psum, 1);
      psum += __shfl_xor(psum, 2);
      psum += __shfl_xor(psum, 4);
      psum += __shfl_xor(psum, 8);
      lrow[jr] = lrow[jr] * corr + psum;
      mrow[jr] = mN;
      o[0][jr] *= corr; o[1][jr] *= corr; o[2][jr] *= corr; o[3][jr] *= corr;
    }

    // write P (bf16) to per-wave LDS, swizzled
    #pragma unroll
    for (int jr = 0; jr < 4; ++jr) {
      int row = 4 * g + jr;
      #pragma unroll
      for (int kb = 0; kb < 4; ++kb) {
        int col = kb * 16 + ln;
        int swc = (col & 7) + 8 * ((col >> 3) ^ (row & 7));
        Ps[w][row * 64 + swc] = f2bf(pv[jr][kb]);
      }
    }

    // PV: O += P[16 x 64] @ V[64 x 64]
    #pragma unroll
    for (int t = 0; t < 2; ++t) {
      bf16x8 ap = *(const bf16x8*)&Ps[w][ln * 64 + (((4 * t + g) ^ (ln & 7)) * 8)];
      #pragma unroll
      for (int dblk = 0; dblk < 4; ++dblk) {
        int r = dblk * 16 + ln;
        bf16x8 bvv = *(const bf16x8*)&Vs[r * 64 + (((4 * t + g) ^ (r & 7)) * 8)];
        o[dblk] = __builtin_amdgcn_mfma_f32_16x16x32_bf16(ap, bvv, o[dblk], 0, 0, 0);
      }
    }
    __syncthreads();
  }

  // normalize + write Y [B,S,E] bf16
  #pragma unroll
  for (int jr = 0; jr < 4; ++jr) {
    float inv = lrow[jr] > 0.f ? 1.0f / lrow[jr] : 0.f;
    int s = qr + 4 * g + jr;
    #pragma unroll
    for (int dblk = 0; dblk < 4; ++dblk) {
      int e = h * HD + dblk * 16 + ln;
      Y[((size_t)b * S_LEN + s) * EMB + e] = f2bf(o[dblk][jr] * inv);
    }
  }
}

// ---------------- GEMM2: Y[8192,1024] @ WpT^T + b -> out f32 ----------------
__global__ __launch_bounds__(256) void gemm_out(
    const u16* __restrict__ A, const u16* __restrict__ Bt,
    const float* __restrict__ bias, float* __restrict__ out) {
  __shared__ u16 As[128 * 32];
  __shared__ u16 Bs[128 * 32];
  const int tid = threadIdx.x;
  const int m0 = blockIdx.x * 128, n0 = blockIdx.y * 128;
  const int w = tid >> 6, lane = tid & 63, g = lane >> 4, ln = lane & 15;
  const int wm = (w >> 1) * 64, wn = (w & 1) * 64;

  f32x4 zero4 = {0.f, 0.f, 0.f, 0.f};
  f32x4 acc[4][4];
  #pragma unroll
  for (int mi = 0; mi < 4; ++mi)
    #pragma unroll
    for (int ni = 0; ni < 4; ++ni) acc[mi][ni] = zero4;

  for (int kt = 0; kt < KDIM / 32; ++kt) {
    #pragma unroll
    for (int p = 0; p < 2; ++p) {
      int idx = p * 256 + tid;
      int row = idx >> 2, sl = idx & 3;
      int ssl = sl ^ (row & 3);
      load_lds16(A  + (size_t)(m0 + row) * KDIM + kt * 32 + ssl * 8, As + idx * 8);
      load_lds16(Bt + (size_t)(n0 + row) * KDIM + kt * 32 + ssl * 8, Bs + idx * 8);
    }
    __syncthreads();
    bf16x8 av[4], bv[4];
    #pragma unroll
    for (int mi = 0; mi < 4; ++mi) {
      int r = wm + mi * 16 + ln;
      av[mi] = *(const bf16x8*)&As[r * 32 + ((g ^ (r & 3)) * 8)];
    }
    #pragma unroll
    for (int ni = 0; ni < 4; ++ni) {
      int r = wn + ni * 16 + ln;
      bv[ni] = *(const bf16x8*)&Bs[r * 32 + ((g ^ (r & 3)) * 8)];
    }
    #pragma unroll
    for (int mi = 0; mi < 4; ++mi)
      #pragma unroll
      for (int ni = 0; ni < 4; ++ni)
        acc[mi][ni] = __builtin_amdgcn_mfma_f32_16x16x32_bf16(av[mi], bv[ni], acc[mi][ni], 0, 0, 0);
    __syncthreads();
  }

  #pragma unroll
  for (int ni = 0; ni < 4; ++ni) {
    int n = n0 + wn + ni * 16 + ln;
    float bb = bias[n];
    #pragma unroll
    for (int mi = 0; mi < 4; ++mi) {
      int m = m0 + wm + mi * 16 + 4 * g;
      #pragma unroll
      for (int jr = 0; jr < 4; ++jr) {
        out[(size_t)(m + jr) * EMB + n] = acc[mi][ni][jr] + bb;
      }
    }
  }
}

extern "C" void kernel_launch(void* const* d_in, const int* in_sizes, int n_in,
                              void* d_out, int out_size, void* d_ws, size_t ws_size,
                              hipStream_t stream) {
  const float* x  = (const float*)d_in[0];
  const int*   am = (const int*)d_in[1];
  const float* Wa = (const float*)d_in[2];
  const float* ba = (const float*)d_in[3];
  const float* Wp = (const float*)d_in[4];
  const float* bp = (const float*)d_in[5];
  float* out = (float*)d_out;

  char* ws = (char*)d_ws;
  u16* Xb  = (u16*)(ws);                               // 16,777,216 B
  u16* WaT = (u16*)(ws + 16777216UL);                  //  6,291,456 B
  u16* WpT = (u16*)(ws + 23068672UL);                  //  2,097,152 B
  u16* Qw  = (u16*)(ws + 25165824UL);                  // 16,777,216 B
  u16* Kw  = (u16*)(ws + 41943040UL);                  // 16,777,216 B
  u16* Vt  = (u16*)(ws + 58720256UL);                  // 16,777,216 B
  u16* Yb  = (u16*)(ws + 75497472UL);                  // 16,777,216 B -> 92,274,688 total

  cvt_x<<<2048, 256, 0, stream>>>((const float4*)x, (ushort4*)Xb, (M_ROWS * EMB) / 4);
  transpose_cvt<<<dim3(N_QKV / 64, KDIM / 64), 256, 0, stream>>>(Wa, WaT, KDIM, N_QKV);
  transpose_cvt<<<dim3(EMB / 64, KDIM / 64), 256, 0, stream>>>(Wp, WpT, KDIM, EMB);
  gemm_qkv<<<dim3(M_ROWS / 128, N_QKV / 128), 256, 0, stream>>>(Xb, WaT, ba, Qw, Kw, Vt);
  attn_kernel<<<dim3(S_LEN / 64, BHN), 256, 0, stream>>>(Qw, Kw, Vt, am, Yb);
  gemm_out<<<dim3(M_ROWS / 128, EMB / 128), 256, 0, stream>>>(Yb, WpT, bp, out);
}

// Round 5
// 313.586 us; speedup vs baseline: 1.6722x; 1.6722x over previous
//
#include <hip/hip_runtime.h>

#define S_LEN 2048
#define EMB   1024
#define NH    16
#define HD    64
#define BATCH_ 4
#define BHN   (BATCH_*NH)        // 64
#define M_ROWS (BATCH_*S_LEN)    // 8192
#define KDIM  1024
#define N_QKV 3072

typedef unsigned short u16;
typedef unsigned long long u64;
typedef __attribute__((ext_vector_type(8))) short bf16x8;
typedef __attribute__((ext_vector_type(4))) float f32x4;
typedef __attribute__((ext_vector_type(16))) float f32x16;

__device__ __forceinline__ u16 f2bf(float f) {
  unsigned u = __float_as_uint(f);
  u += 0x7fff + ((u >> 16) & 1);
  return (u16)(u >> 16);
}

__device__ __forceinline__ void load_lds16(const void* g, void* l) {
  __builtin_amdgcn_global_load_lds(
      (const __attribute__((address_space(1))) unsigned int*)g,
      (__attribute__((address_space(3))) unsigned int*)l, 16, 0, 0);
}

// ---------------- convert x -> bf16 ----------------
__global__ void cvt_x(const float4* __restrict__ in, ushort4* __restrict__ outb, int n4) {
  int i = blockIdx.x * blockDim.x + threadIdx.x;
  int stride = gridDim.x * blockDim.x;
  for (; i < n4; i += stride) {
    float4 v = in[i];
    ushort4 o;
    o.x = f2bf(v.x); o.y = f2bf(v.y); o.z = f2bf(v.z); o.w = f2bf(v.w);
    outb[i] = o;
  }
}

// ------------- transpose-convert W[R][C] f32 -> Wt[C][R] bf16 -------------
__global__ __launch_bounds__(256) void transpose_cvt(
    const float* __restrict__ W, u16* __restrict__ Wt, int R, int C) {
  __shared__ u16 t[64][65];
  int r0 = blockIdx.y * 64, c0 = blockIdx.x * 64;
  #pragma unroll
  for (int p = 0; p < 16; ++p) {
    int idx = p * 256 + threadIdx.x;
    int r = idx >> 6, c = idx & 63;
    t[r][c] = f2bf(W[(size_t)(r0 + r) * C + c0 + c]);
  }
  __syncthreads();
  #pragma unroll
  for (int p = 0; p < 16; ++p) {
    int idx = p * 256 + threadIdx.x;
    int cc = idx >> 6, rr = idx & 63;
    Wt[(size_t)(c0 + cc) * R + r0 + rr] = t[rr][cc];
  }
}

// ---------------- GEMM1: X[8192,1024] @ WaT^T -> Q(scaled),K,V^T (bf16) ----------------
__global__ __launch_bounds__(256) void gemm_qkv(
    const u16* __restrict__ A, const u16* __restrict__ Bt,
    const float* __restrict__ bias,
    u16* __restrict__ Qo, u16* __restrict__ Ko, u16* __restrict__ Vto) {
  __shared__ u16 As[128 * 32];
  __shared__ u16 Bs[128 * 32];
  const int tid = threadIdx.x;
  const int m0 = blockIdx.x * 128, n0 = blockIdx.y * 128;
  const int w = tid >> 6, lane = tid & 63, g = lane >> 4, ln = lane & 15;
  const int wm = (w >> 1) * 64, wn = (w & 1) * 64;

  f32x4 zero4 = {0.f, 0.f, 0.f, 0.f};
  f32x4 acc[4][4];
  #pragma unroll
  for (int mi = 0; mi < 4; ++mi)
    #pragma unroll
    for (int ni = 0; ni < 4; ++ni) acc[mi][ni] = zero4;

  for (int kt = 0; kt < KDIM / 32; ++kt) {
    #pragma unroll
    for (int p = 0; p < 2; ++p) {
      int idx = p * 256 + tid;
      int row = idx >> 2, sl = idx & 3;
      int ssl = sl ^ (row & 3);
      load_lds16(A  + (size_t)(m0 + row) * KDIM + kt * 32 + ssl * 8, As + idx * 8);
      load_lds16(Bt + (size_t)(n0 + row) * KDIM + kt * 32 + ssl * 8, Bs + idx * 8);
    }
    __syncthreads();
    bf16x8 av[4], bv[4];
    #pragma unroll
    for (int mi = 0; mi < 4; ++mi) {
      int r = wm + mi * 16 + ln;
      av[mi] = *(const bf16x8*)&As[r * 32 + ((g ^ (r & 3)) * 8)];
    }
    #pragma unroll
    for (int ni = 0; ni < 4; ++ni) {
      int r = wn + ni * 16 + ln;
      bv[ni] = *(const bf16x8*)&Bs[r * 32 + ((g ^ (r & 3)) * 8)];
    }
    #pragma unroll
    for (int mi = 0; mi < 4; ++mi)
      #pragma unroll
      for (int ni = 0; ni < 4; ++ni)
        acc[mi][ni] = __builtin_amdgcn_mfma_f32_16x16x32_bf16(av[mi], bv[ni], acc[mi][ni], 0, 0, 0);
    __syncthreads();
  }

  // epilogue: bias add (+ 1/8 scale folded into Q), scatter
  #pragma unroll
  for (int ni = 0; ni < 4; ++ni) {
    int n = n0 + wn + ni * 16 + ln;
    float bb = bias[n];
    int which = n >> 10;             // 0=Q 1=K 2=V
    float qs = (which == 0) ? 0.125f : 1.0f;
    int e = n & 1023;
    int h = e >> 6, d = e & 63;
    #pragma unroll
    for (int mi = 0; mi < 4; ++mi) {
      int m = m0 + wm + mi * 16 + 4 * g;
      int b = m >> 11, s = m & 2047;
      size_t bh = (size_t)b * NH + h;
      #pragma unroll
      for (int jr = 0; jr < 4; ++jr) {
        u16 val = f2bf((acc[mi][ni][jr] + bb) * qs);
        if (which == 0)      Qo [(bh * S_LEN + s + jr) * HD + d] = val;
        else if (which == 1) Ko [(bh * S_LEN + s + jr) * HD + d] = val;
        else                 Vto[(bh * HD + d) * S_LEN + s + jr] = val;
      }
    }
  }
}

// ---------------- flash attention, swapped-QK 32x32 structure ----------------
// 4 warps x 32 q-rows = 128 q/block. KV tile = 64 keys, double-buffered LDS,
// 16B-slot XOR swizzle (pre-swizzled global_load_lds source).
__global__ __launch_bounds__(256, 2) void attn3(
    const u16* __restrict__ Q, const u16* __restrict__ Kg,
    const u16* __restrict__ Vt, const int* __restrict__ amask,
    u16* __restrict__ Y) {
  __shared__ u16 Kl[2][4096];   // [buf][64 rows x 64 u16], swizzled 16B slots
  __shared__ u16 Vl[2][4096];   // [buf][64 d-rows x 64 keys]
  __shared__ u16 OL[128][72];   // epilogue transpose (stride 72: 144B, 16B-mult)

  // XCD-chunked bijective swizzle: 1024 blocks, XCD j gets flat [j*128,(j+1)*128)
  int flat = ((blockIdx.x & 7) << 7) + (blockIdx.x >> 3);
  const int bh = flat >> 4;
  const int qblk = 15 - (flat & 15);      // long blocks first within chunk
  const int b = bh >> 4, h = bh & 15;
  const int q0 = qblk * 128;
  const int tid = threadIdx.x, w = tid >> 6, lane = tid & 63;
  const int hi = lane >> 5, lq = lane & 31;
  const int qrow = q0 + 32 * w + lq;      // this lane's q-row

  // Q fragments: 4 x bf16x8 (dim = 16*st + 8*hi + j), pre-scaled by 1/8
  bf16x8 qf[4];
  {
    const u16* qp = Q + ((size_t)bh * S_LEN + qrow) * HD + hi * 8;
    #pragma unroll
    for (int st = 0; st < 4; ++st) qf[st] = *(const bf16x8*)(qp + st * 16);
  }

  f32x16 o0, o1;
  #pragma unroll
  for (int i = 0; i < 16; ++i) { o0[i] = 0.f; o1[i] = 0.f; }
  float m_run = -1.0e30f, l_run = 0.f;

  auto STAGE = [&](int buf, int kt) {
    #pragma unroll
    for (int c = 0; c < 2; ++c) {
      int gi = c * 256 + tid;
      int r = gi >> 3, s = gi & 7;
      int soff = (s ^ (r & 7)) << 3;       // pre-swizzled source elem offset
      load_lds16(Kg + ((size_t)bh * S_LEN + kt * 64 + r) * HD + soff, &Kl[buf][gi << 3]);
      load_lds16(Vt + ((size_t)bh * HD + r) * S_LEN + kt * 64 + soff, &Vl[buf][gi << 3]);
    }
  };

  const int nt = (q0 + 128) >> 6;
  STAGE(0, 0);
  __syncthreads();

  for (int kt = 0; kt < nt; ++kt) {
    const int cur = kt & 1;
    if (kt + 1 < nt) STAGE(cur ^ 1, kt + 1);
    const int kbase = kt << 6;
    if (kbase <= q0 + 32 * w + 31) {       // warp-active (uniform)
      // ---- QK^T (swapped): S^T[key][q], q = lane&31 ----
      f32x16 s0, s1;
      #pragma unroll
      for (int i = 0; i < 16; ++i) { s0[i] = 0.f; s1[i] = 0.f; }
      #pragma unroll
      for (int st = 0; st < 4; ++st) {
        int r0 = lq;
        bf16x8 kf0 = *(const bf16x8*)&Kl[cur][(r0 << 6) + (((2 * st + hi) ^ (r0 & 7)) << 3)];
        s0 = __builtin_amdgcn_mfma_f32_32x32x16_bf16(kf0, qf[st], s0, 0, 0, 0);
        int r1 = 32 + lq;
        bf16x8 kf1 = *(const bf16x8*)&Kl[cur][(r1 << 6) + (((2 * st + hi) ^ (r1 & 7)) << 3)];
        s1 = __builtin_amdgcn_mfma_f32_32x32x16_bf16(kf1, qf[st], s1, 0, 0, 0);
      }
      // ---- masking: causal only near diagonal; amask via ballot ----
      u64 mb = __ballot(amask[b * S_LEN + kbase + lane] != 0);
      bool needc = (kbase + 63) > (q0 + 32 * w);
      if (needc || mb != ~0ull) {
        #pragma unroll
        for (int r = 0; r < 16; ++r) {
          int kl0 = (r & 3) + 8 * (r >> 2) + 4 * hi;
          int kl1 = kl0 + 32;
          if (kbase + kl0 > qrow || !((mb >> kl0) & 1)) s0[r] = -__builtin_inff();
          if (kbase + kl1 > qrow || !((mb >> kl1) & 1)) s1[r] = -__builtin_inff();
        }
      }
      // ---- online softmax (always rescale; all values finite-safe) ----
      float pm = s0[0];
      #pragma unroll
      for (int r = 1; r < 16; ++r) pm = fmaxf(pm, s0[r]);
      #pragma unroll
      for (int r = 0; r < 16; ++r) pm = fmaxf(pm, s1[r]);
      pm = fmaxf(pm, __shfl_xor(pm, 32));
      float mN = fmaxf(m_run, pm);          // finite: m_run init -1e30
      float corr = __expf(m_run - mN);      // in [0,1]
      l_run *= corr;
      #pragma unroll
      for (int i = 0; i < 16; ++i) { o0[i] *= corr; o1[i] *= corr; }
      float psum = 0.f;
      #pragma unroll
      for (int r = 0; r < 16; ++r) { s0[r] = __expf(s0[r] - mN); psum += s0[r]; }
      #pragma unroll
      for (int r = 0; r < 16; ++r) { s1[r] = __expf(s1[r] - mN); psum += s1[r]; }
      psum += __shfl_xor(psum, 32);
      l_run += psum;
      m_run = mN;
      // ---- pack P to bf16 frags (plain converts) ----
      bf16x8 pa[4];
      #pragma unroll
      for (int g = 0; g < 4; ++g) {
        union { u16 us[8]; bf16x8 v; } pu;
        #pragma unroll
        for (int j = 0; j < 8; ++j) {
          float p = (g & 2) ? s1[(g & 1) * 8 + j] : s0[(g & 1) * 8 + j];
          pu.us[j] = f2bf(p);
        }
        pa[g] = pu.v;
      }
      // ---- PV (swapped): O^T[d][q] += V^T-frag x P-frag ----
      #pragma unroll
      for (int sub = 0; sub < 2; ++sub) {
        int r = (sub << 5) + lq;           // d-row in V tile
        #pragma unroll
        for (int g = 0; g < 4; ++g) {
          union { short4 s4[2]; bf16x8 v; } vu;
          vu.s4[0] = *(const short4*)&Vl[cur][(r << 6) + ((((2 * g)     ^ (r & 7)) << 3) + (hi << 2))];
          vu.s4[1] = *(const short4*)&Vl[cur][(r << 6) + ((((2 * g + 1) ^ (r & 7)) << 3) + (hi << 2))];
          if (sub == 0) o0 = __builtin_amdgcn_mfma_f32_32x32x16_bf16(vu.v, pa[g], o0, 0, 0, 0);
          else          o1 = __builtin_amdgcn_mfma_f32_32x32x16_bf16(vu.v, pa[g], o1, 0, 0, 0);
        }
      }
    }
    __syncthreads();
  }

  // ---- epilogue: normalize, transpose via dedicated LDS, coalesced Y write ----
  float inv = l_run > 0.f ? 1.f / l_run : 0.f;
  #pragma unroll
  for (int sub = 0; sub < 2; ++sub) {
    #pragma unroll
    for (int r = 0; r < 16; ++r) {
      int d = (sub << 5) + (r & 3) + 8 * (r >> 2) + 4 * hi;
      OL[32 * w + lq][d] = f2bf((sub ? o1[r] : o0[r]) * inv);
    }
  }
  __syncthreads();
  {
    int row = tid >> 1, half = tid & 1;
    const u16* src = &OL[row][half * 32];
    u16* yp = Y + ((size_t)b * S_LEN + q0 + row) * EMB + h * HD + half * 32;
    #pragma unroll
    for (int c = 0; c < 4; ++c)
      *(bf16x8*)(yp + 8 * c) = *(const bf16x8*)(src + 8 * c);
  }
}

// ---------------- GEMM2: Y[8192,1024] @ WpT^T + b -> out f32 ----------------
__global__ __launch_bounds__(256) void gemm_out(
    const u16* __restrict__ A, const u16* __restrict__ Bt,
    const float* __restrict__ bias, float* __restrict__ out) {
  __shared__ u16 As[128 * 32];
  __shared__ u16 Bs[128 * 32];
  const int tid = threadIdx.x;
  const int m0 = blockIdx.x * 128, n0 = blockIdx.y * 128;
  const int w = tid >> 6, lane = tid & 63, g = lane >> 4, ln = lane & 15;
  const int wm = (w >> 1) * 64, wn = (w & 1) * 64;

  f32x4 zero4 = {0.f, 0.f, 0.f, 0.f};
  f32x4 acc[4][4];
  #pragma unroll
  for (int mi = 0; mi < 4; ++mi)
    #pragma unroll
    for (int ni = 0; ni < 4; ++ni) acc[mi][ni] = zero4;

  for (int kt = 0; kt < KDIM / 32; ++kt) {
    #pragma unroll
    for (int p = 0; p < 2; ++p) {
      int idx = p * 256 + tid;
      int row = idx >> 2, sl = idx & 3;
      int ssl = sl ^ (row & 3);
      load_lds16(A  + (size_t)(m0 + row) * KDIM + kt * 32 + ssl * 8, As + idx * 8);
      load_lds16(Bt + (size_t)(n0 + row) * KDIM + kt * 32 + ssl * 8, Bs + idx * 8);
    }
    __syncthreads();
    bf16x8 av[4], bv[4];
    #pragma unroll
    for (int mi = 0; mi < 4; ++mi) {
      int r = wm + mi * 16 + ln;
      av[mi] = *(const bf16x8*)&As[r * 32 + ((g ^ (r & 3)) * 8)];
    }
    #pragma unroll
    for (int ni = 0; ni < 4; ++ni) {
      int r = wn + ni * 16 + ln;
      bv[ni] = *(const bf16x8*)&Bs[r * 32 + ((g ^ (r & 3)) * 8)];
    }
    #pragma unroll
    for (int mi = 0; mi < 4; ++mi)
      #pragma unroll
      for (int ni = 0; ni < 4; ++ni)
        acc[mi][ni] = __builtin_amdgcn_mfma_f32_16x16x32_bf16(av[mi], bv[ni], acc[mi][ni], 0, 0, 0);
    __syncthreads();
  }

  #pragma unroll
  for (int ni = 0; ni < 4; ++ni) {
    int n = n0 + wn + ni * 16 + ln;
    float bb = bias[n];
    #pragma unroll
    for (int mi = 0; mi < 4; ++mi) {
      int m = m0 + wm + mi * 16 + 4 * g;
      #pragma unroll
      for (int jr = 0; jr < 4; ++jr) {
        out[(size_t)(m + jr) * EMB + n] = acc[mi][ni][jr] + bb;
      }
    }
  }
}

extern "C" void kernel_launch(void* const* d_in, const int* in_sizes, int n_in,
                              void* d_out, int out_size, void* d_ws, size_t ws_size,
                              hipStream_t stream) {
  const float* x  = (const float*)d_in[0];
  const int*   am = (const int*)d_in[1];
  const float* Wa = (const float*)d_in[2];
  const float* ba = (const float*)d_in[3];
  const float* Wp = (const float*)d_in[4];
  const float* bp = (const float*)d_in[5];
  float* out = (float*)d_out;

  char* ws = (char*)d_ws;
  u16* Xb  = (u16*)(ws);                               // 16,777,216 B
  u16* WaT = (u16*)(ws + 16777216UL);                  //  6,291,456 B
  u16* WpT = (u16*)(ws + 23068672UL);                  //  2,097,152 B
  u16* Qw  = (u16*)(ws + 25165824UL);                  // 16,777,216 B
  u16* Kw  = (u16*)(ws + 41943040UL);                  // 16,777,216 B
  u16* Vt  = (u16*)(ws + 58720256UL);                  // 16,777,216 B
  u16* Yb  = (u16*)(ws + 75497472UL);                  // 16,777,216 B -> 92,274,688 total

  cvt_x<<<2048, 256, 0, stream>>>((const float4*)x, (ushort4*)Xb, (M_ROWS * EMB) / 4);
  transpose_cvt<<<dim3(N_QKV / 64, KDIM / 64), 256, 0, stream>>>(Wa, WaT, KDIM, N_QKV);
  transpose_cvt<<<dim3(EMB / 64, KDIM / 64), 256, 0, stream>>>(Wp, WpT, KDIM, EMB);
  gemm_qkv<<<dim3(M_ROWS / 128, N_QKV / 128), 256, 0, stream>>>(Xb, WaT, ba, Qw, Kw, Vt);
  attn3<<<1024, 256, 0, stream>>>(Qw, Kw, Vt, am, Yb);
  gemm_out<<<dim3(M_ROWS / 128, EMB / 128), 256, 0, stream>>>(Yb, WpT, bp, out);
}

// Round 12
// 307.319 us; speedup vs baseline: 1.7063x; 1.0204x over previous
//
#include <hip/hip_runtime.h>

#define S_LEN 2048
#define EMB   1024
#define NH    16
#define HD    64
#define BATCH_ 4
#define BHN   (BATCH_*NH)        // 64
#define M_ROWS (BATCH_*S_LEN)    // 8192
#define KDIM  1024
#define N_QKV 3072

typedef unsigned short u16;
typedef unsigned int u32;
typedef unsigned long long u64;
typedef __attribute__((ext_vector_type(8))) short bf16x8;
typedef __attribute__((ext_vector_type(4))) float f32x4;
typedef __attribute__((ext_vector_type(16))) float f32x16;

__device__ __forceinline__ u16 f2bf(float f) {
  unsigned u = __float_as_uint(f);
  u += 0x7fff + ((u >> 16) & 1);
  return (u16)(u >> 16);
}

__device__ __forceinline__ void load_lds16(const void* g, void* l) {
  __builtin_amdgcn_global_load_lds(
      (const __attribute__((address_space(1))) unsigned int*)g,
      (__attribute__((address_space(3))) unsigned int*)l, 16, 0, 0);
}

// ---------------- convert x -> bf16 ----------------
__global__ void cvt_x(const float4* __restrict__ in, ushort4* __restrict__ outb, int n4) {
  int i = blockIdx.x * blockDim.x + threadIdx.x;
  int stride = gridDim.x * blockDim.x;
  for (; i < n4; i += stride) {
    float4 v = in[i];
    ushort4 o;
    o.x = f2bf(v.x); o.y = f2bf(v.y); o.z = f2bf(v.z); o.w = f2bf(v.w);
    outb[i] = o;
  }
}

// ------------- transpose-convert W[R][C] f32 -> Wt[C][R] bf16 -------------
__global__ __launch_bounds__(256) void transpose_cvt(
    const float* __restrict__ W, u16* __restrict__ Wt, int R, int C) {
  __shared__ u16 t[64][65];
  int r0 = blockIdx.y * 64, c0 = blockIdx.x * 64;
  #pragma unroll
  for (int p = 0; p < 16; ++p) {
    int idx = p * 256 + threadIdx.x;
    int r = idx >> 6, c = idx & 63;
    t[r][c] = f2bf(W[(size_t)(r0 + r) * C + c0 + c]);
  }
  __syncthreads();
  #pragma unroll
  for (int p = 0; p < 16; ++p) {
    int idx = p * 256 + threadIdx.x;
    int cc = idx >> 6, rr = idx & 63;
    Wt[(size_t)(c0 + cc) * R + r0 + rr] = t[rr][cc];
  }
}

// ---------------- GEMM1: X[8192,1024] @ WaT^T -> Q(scaled),K,V^T (bf16) ----------------
__global__ __launch_bounds__(256) void gemm_qkv(
    const u16* __restrict__ A, const u16* __restrict__ Bt,
    const float* __restrict__ bias,
    u16* __restrict__ Qo, u16* __restrict__ Ko, u16* __restrict__ Vto) {
  __shared__ u16 As[128 * 32];
  __shared__ u16 Bs[128 * 32];
  const int tid = threadIdx.x;
  const int m0 = blockIdx.x * 128, n0 = blockIdx.y * 128;
  const int w = tid >> 6, lane = tid & 63, g = lane >> 4, ln = lane & 15;
  const int wm = (w >> 1) * 64, wn = (w & 1) * 64;

  f32x4 zero4 = {0.f, 0.f, 0.f, 0.f};
  f32x4 acc[4][4];
  #pragma unroll
  for (int mi = 0; mi < 4; ++mi)
    #pragma unroll
    for (int ni = 0; ni < 4; ++ni) acc[mi][ni] = zero4;

  for (int kt = 0; kt < KDIM / 32; ++kt) {
    #pragma unroll
    for (int p = 0; p < 2; ++p) {
      int idx = p * 256 + tid;
      int row = idx >> 2, sl = idx & 3;
      int ssl = sl ^ (row & 3);
      load_lds16(A  + (size_t)(m0 + row) * KDIM + kt * 32 + ssl * 8, As + idx * 8);
      load_lds16(Bt + (size_t)(n0 + row) * KDIM + kt * 32 + ssl * 8, Bs + idx * 8);
    }
    __syncthreads();
    bf16x8 av[4], bv[4];
    #pragma unroll
    for (int mi = 0; mi < 4; ++mi) {
      int r = wm + mi * 16 + ln;
      av[mi] = *(const bf16x8*)&As[r * 32 + ((g ^ (r & 3)) * 8)];
    }
    #pragma unroll
    for (int ni = 0; ni < 4; ++ni) {
      int r = wn + ni * 16 + ln;
      bv[ni] = *(const bf16x8*)&Bs[r * 32 + ((g ^ (r & 3)) * 8)];
    }
    #pragma unroll
    for (int mi = 0; mi < 4; ++mi)
      #pragma unroll
      for (int ni = 0; ni < 4; ++ni)
        acc[mi][ni] = __builtin_amdgcn_mfma_f32_16x16x32_bf16(av[mi], bv[ni], acc[mi][ni], 0, 0, 0);
    __syncthreads();
  }

  // epilogue: bias add (+ (1/8)*log2(e) folded into Q for exp2-domain softmax), scatter
  #pragma unroll
  for (int ni = 0; ni < 4; ++ni) {
    int n = n0 + wn + ni * 16 + ln;
    float bb = bias[n];
    int which = n >> 10;             // 0=Q 1=K 2=V
    float qs = (which == 0) ? 0.18033688011f : 1.0f;   // 0.125 * log2(e)
    int e = n & 1023;
    int h = e >> 6, d = e & 63;
    #pragma unroll
    for (int mi = 0; mi < 4; ++mi) {
      int m = m0 + wm + mi * 16 + 4 * g;
      int b = m >> 11, s = m & 2047;
      size_t bh = (size_t)b * NH + h;
      #pragma unroll
      for (int jr = 0; jr < 4; ++jr) {
        u16 val = f2bf((acc[mi][ni][jr] + bb) * qs);
        if (which == 0)      Qo [(bh * S_LEN + s + jr) * HD + d] = val;
        else if (which == 1) Ko [(bh * S_LEN + s + jr) * HD + d] = val;
        else                 Vto[(bh * HD + d) * S_LEN + s + jr] = val;
      }
    }
  }
}

// ---------------- flash attention, swapped-QK 32x32 structure ----------------
// 4 warps x 32 q-rows = 128 q/block. KV tile = 64 keys, double-buffered LDS,
// 16B-slot XOR swizzle (pre-swizzled global_load_lds source).
// R9: R5 baseline + exp2-domain softmax ONLY (pkbf asm BANNED: convicted of NaN in R8).
__global__ __launch_bounds__(256, 2) void attn3(
    const u16* __restrict__ Q, const u16* __restrict__ Kg,
    const u16* __restrict__ Vt, const int* __restrict__ amask,
    u16* __restrict__ Y) {
  __shared__ u16 Kl[2][4096];   // [buf][64 rows x 64 u16], swizzled 16B slots
  __shared__ u16 Vl[2][4096];   // [buf][64 d-rows x 64 keys]
  __shared__ u16 OL[128][72];   // epilogue transpose (stride 72: 144B, 16B-mult)

  // XCD-chunked bijective swizzle: 1024 blocks, XCD j gets flat [j*128,(j+1)*128)
  int flat = ((blockIdx.x & 7) << 7) + (blockIdx.x >> 3);
  const int bh = flat >> 4;
  const int qblk = 15 - (flat & 15);      // long blocks first within chunk
  const int b = bh >> 4, h = bh & 15;
  const int q0 = qblk * 128;
  const int tid = threadIdx.x, w = tid >> 6, lane = tid & 63;
  const int hi = lane >> 5, lq = lane & 31;
  const int qrow = q0 + 32 * w + lq;      // this lane's q-row

  // Q fragments: 4 x bf16x8 (dim = 16*st + 8*hi + j), pre-scaled
  bf16x8 qf[4];
  {
    const u16* qp = Q + ((size_t)bh * S_LEN + qrow) * HD + hi * 8;
    #pragma unroll
    for (int st = 0; st < 4; ++st) qf[st] = *(const bf16x8*)(qp + st * 16);
  }

  f32x16 o0, o1;
  #pragma unroll
  for (int i = 0; i < 16; ++i) { o0[i] = 0.f; o1[i] = 0.f; }
  float m_run = -1.0e30f, l_run = 0.f;

  auto STAGE = [&](int buf, int kt) {
    #pragma unroll
    for (int c = 0; c < 2; ++c) {
      int gi = c * 256 + tid;
      int r = gi >> 3, s = gi & 7;
      int soff = (s ^ (r & 7)) << 3;       // pre-swizzled source elem offset
      load_lds16(Kg + ((size_t)bh * S_LEN + kt * 64 + r) * HD + soff, &Kl[buf][gi << 3]);
      load_lds16(Vt + ((size_t)bh * HD + r) * S_LEN + kt * 64 + soff, &Vl[buf][gi << 3]);
    }
  };

  const int nt = (q0 + 128) >> 6;
  STAGE(0, 0);
  __syncthreads();

  for (int kt = 0; kt < nt; ++kt) {
    const int cur = kt & 1;
    if (kt + 1 < nt) STAGE(cur ^ 1, kt + 1);
    const int kbase = kt << 6;
    if (kbase <= q0 + 32 * w + 31) {       // warp-active (uniform)
      // ---- QK^T (swapped): S^T[key][q], q = lane&31; scores in log2 units ----
      f32x16 s0, s1;
      #pragma unroll
      for (int i = 0; i < 16; ++i) { s0[i] = 0.f; s1[i] = 0.f; }
      #pragma unroll
      for (int st = 0; st < 4; ++st) {
        int r0 = lq;
        bf16x8 kf0 = *(const bf16x8*)&Kl[cur][(r0 << 6) + (((2 * st + hi) ^ (r0 & 7)) << 3)];
        s0 = __builtin_amdgcn_mfma_f32_32x32x16_bf16(kf0, qf[st], s0, 0, 0, 0);
        int r1 = 32 + lq;
        bf16x8 kf1 = *(const bf16x8*)&Kl[cur][(r1 << 6) + (((2 * st + hi) ^ (r1 & 7)) << 3)];
        s1 = __builtin_amdgcn_mfma_f32_32x32x16_bf16(kf1, qf[st], s1, 0, 0, 0);
      }
      // ---- masking: causal only near diagonal; amask via ballot ----
      u64 mb = __ballot(amask[b * S_LEN + kbase + lane] != 0);
      bool needc = (kbase + 63) > (q0 + 32 * w);
      if (needc || mb != ~0ull) {
        #pragma unroll
        for (int r = 0; r < 16; ++r) {
          int kl0 = (r & 3) + 8 * (r >> 2) + 4 * hi;
          int kl1 = kl0 + 32;
          if (kbase + kl0 > qrow || !((mb >> kl0) & 1)) s0[r] = -__builtin_inff();
          if (kbase + kl1 > qrow || !((mb >> kl1) & 1)) s1[r] = -__builtin_inff();
        }
      }
      // ---- online softmax in exp2 domain (always rescale; finite-safe) ----
      float pm = s0[0];
      #pragma unroll
      for (int r = 1; r < 16; ++r) pm = fmaxf(pm, s0[r]);
      #pragma unroll
      for (int r = 0; r < 16; ++r) pm = fmaxf(pm, s1[r]);
      pm = fmaxf(pm, __shfl_xor(pm, 32));
      float mN = fmaxf(m_run, pm);          // finite: m_run init -1e30
      float corr = __builtin_amdgcn_exp2f(m_run - mN);   // in [0,1]
      l_run *= corr;
      #pragma unroll
      for (int i = 0; i < 16; ++i) { o0[i] *= corr; o1[i] *= corr; }
      float psum = 0.f;
      #pragma unroll
      for (int r = 0; r < 16; ++r) { s0[r] = __builtin_amdgcn_exp2f(s0[r] - mN); psum += s0[r]; }
      #pragma unroll
      for (int r = 0; r < 16; ++r) { s1[r] = __builtin_amdgcn_exp2f(s1[r] - mN); psum += s1[r]; }
      psum += __shfl_xor(psum, 32);
      l_run += psum;
      m_run = mN;
      // ---- pack P to bf16 frags (plain converts; R5-proven) ----
      bf16x8 pa[4];
      #pragma unroll
      for (int g = 0; g < 4; ++g) {
        union { u16 us[8]; bf16x8 v; } pu;
        #pragma unroll
        for (int j = 0; j < 8; ++j) {
          float p = (g & 2) ? s1[(g & 1) * 8 + j] : s0[(g & 1) * 8 + j];
          pu.us[j] = f2bf(p);
        }
        pa[g] = pu.v;
      }
      // ---- PV (swapped): O^T[d][q] += V^T-frag x P-frag ----
      #pragma unroll
      for (int sub = 0; sub < 2; ++sub) {
        int r = (sub << 5) + lq;           // d-row in V tile
        #pragma unroll
        for (int g = 0; g < 4; ++g) {
          union { short4 s4[2]; bf16x8 v; } vu;
          vu.s4[0] = *(const short4*)&Vl[cur][(r << 6) + ((((2 * g)     ^ (r & 7)) << 3) + (hi << 2))];
          vu.s4[1] = *(const short4*)&Vl[cur][(r << 6) + ((((2 * g + 1) ^ (r & 7)) << 3) + (hi << 2))];
          if (sub == 0) o0 = __builtin_amdgcn_mfma_f32_32x32x16_bf16(vu.v, pa[g], o0, 0, 0, 0);
          else          o1 = __builtin_amdgcn_mfma_f32_32x32x16_bf16(vu.v, pa[g], o1, 0, 0, 0);
        }
      }
    }
    __syncthreads();
  }

  // ---- epilogue: normalize, transpose via dedicated LDS, coalesced Y write (R5-proven) ----
  float inv = l_run > 0.f ? 1.f / l_run : 0.f;
  #pragma unroll
  for (int sub = 0; sub < 2; ++sub) {
    #pragma unroll
    for (int r = 0; r < 16; ++r) {
      int d = (sub << 5) + (r & 3) + 8 * (r >> 2) + 4 * hi;
      OL[32 * w + lq][d] = f2bf((sub ? o1[r] : o0[r]) * inv);
    }
  }
  __syncthreads();
  {
    int row = tid >> 1, half = tid & 1;
    const u16* src = &OL[row][half * 32];
    u16* yp = Y + ((size_t)b * S_LEN + q0 + row) * EMB + h * HD + half * 32;
    #pragma unroll
    for (int c = 0; c < 4; ++c)
      *(bf16x8*)(yp + 8 * c) = *(const bf16x8*)(src + 8 * c);
  }
}

// ---------------- GEMM2: Y[8192,1024] @ WpT^T + b -> out f32 ----------------
__global__ __launch_bounds__(256) void gemm_out(
    const u16* __restrict__ A, const u16* __restrict__ Bt,
    const float* __restrict__ bias, float* __restrict__ out) {
  __shared__ u16 As[128 * 32];
  __shared__ u16 Bs[128 * 32];
  const int tid = threadIdx.x;
  const int m0 = blockIdx.x * 128, n0 = blockIdx.y * 128;
  const int w = tid >> 6, lane = tid & 63, g = lane >> 4, ln = lane & 15;
  const int wm = (w >> 1) * 64, wn = (w & 1) * 64;

  f32x4 zero4 = {0.f, 0.f, 0.f, 0.f};
  f32x4 acc[4][4];
  #pragma unroll
  for (int mi = 0; mi < 4; ++mi)
    #pragma unroll
    for (int ni = 0; ni < 4; ++ni) acc[mi][ni] = zero4;

  for (int kt = 0; kt < KDIM / 32; ++kt) {
    #pragma unroll
    for (int p = 0; p < 2; ++p) {
      int idx = p * 256 + tid;
      int row = idx >> 2, sl = idx & 3;
      int ssl = sl ^ (row & 3);
      load_lds16(A  + (size_t)(m0 + row) * KDIM + kt * 32 + ssl * 8, As + idx * 8);
      load_lds16(Bt + (size_t)(n0 + row) * KDIM + kt * 32 + ssl * 8, Bs + idx * 8);
    }
    __syncthreads();
    bf16x8 av[4], bv[4];
    #pragma unroll
    for (int mi = 0; mi < 4; ++mi) {
      int r = wm + mi * 16 + ln;
      av[mi] = *(const bf16x8*)&As[r * 32 + ((g ^ (r & 3)) * 8)];
    }
    #pragma unroll
    for (int ni = 0; ni < 4; ++ni) {
      int r = wn + ni * 16 + ln;
      bv[ni] = *(const bf16x8*)&Bs[r * 32 + ((g ^ (r & 3)) * 8)];
    }
    #pragma unroll
    for (int mi = 0; mi < 4; ++mi)
      #pragma unroll
      for (int ni = 0; ni < 4; ++ni)
        acc[mi][ni] = __builtin_amdgcn_mfma_f32_16x16x32_bf16(av[mi], bv[ni], acc[mi][ni], 0, 0, 0);
    __syncthreads();
  }

  #pragma unroll
  for (int ni = 0; ni < 4; ++ni) {
    int n = n0 + wn + ni * 16 + ln;
    float bb = bias[n];
    #pragma unroll
    for (int mi = 0; mi < 4; ++mi) {
      int m = m0 + wm + mi * 16 + 4 * g;
      #pragma unroll
      for (int jr = 0; jr < 4; ++jr) {
        out[(size_t)(m + jr) * EMB + n] = acc[mi][ni][jr] + bb;
      }
    }
  }
}

extern "C" void kernel_launch(void* const* d_in, const int* in_sizes, int n_in,
                              void* d_out, int out_size, void* d_ws, size_t ws_size,
                              hipStream_t stream) {
  const float* x  = (const float*)d_in[0];
  const int*   am = (const int*)d_in[1];
  const float* Wa = (const float*)d_in[2];
  const float* ba = (const float*)d_in[3];
  const float* Wp = (const float*)d_in[4];
  const float* bp = (const float*)d_in[5];
  float* out = (float*)d_out;

  char* ws = (char*)d_ws;
  u16* Xb  = (u16*)(ws);                               // 16,777,216 B
  u16* WaT = (u16*)(ws + 16777216UL);                  //  6,291,456 B
  u16* WpT = (u16*)(ws + 23068672UL);                  //  2,097,152 B
  u16* Qw  = (u16*)(ws + 25165824UL);                  // 16,777,216 B
  u16* Kw  = (u16*)(ws + 41943040UL);                  // 16,777,216 B
  u16* Vt  = (u16*)(ws + 58720256UL);                  // 16,777,216 B
  u16* Yb  = (u16*)(ws + 75497472UL);                  // 16,777,216 B -> 92,274,688 total

  cvt_x<<<2048, 256, 0, stream>>>((const float4*)x, (ushort4*)Xb, (M_ROWS * EMB) / 4);
  transpose_cvt<<<dim3(N_QKV / 64, KDIM / 64), 256, 0, stream>>>(Wa, WaT, KDIM, N_QKV);
  transpose_cvt<<<dim3(EMB / 64, KDIM / 64), 256, 0, stream>>>(Wp, WpT, KDIM, EMB);
  gemm_qkv<<<dim3(M_ROWS / 128, N_QKV / 128), 256, 0, stream>>>(Xb, WaT, ba, Qw, Kw, Vt);
  attn3<<<1024, 256, 0, stream>>>(Qw, Kw, Vt, am, Yb);
  gemm_out<<<dim3(M_ROWS / 128, EMB / 128), 256, 0, stream>>>(Yb, WpT, bp, out);
}